// Round 4
// baseline (10788.265 us; speedup 1.0000x reference)
//
#include <hip/hip_runtime.h>
#include <math.h>

#define HIDC 128
#define EDGEF 16
#define LAY 3
#define KNN 3
#define UU 4
#define NBLK 20000
#define NATOM (NBLK*UU)      // 80000
#define EBK 30000
#define EALL (EBK*UU*KNN)    // 360000

#define W1F_L 36864          // 9 kb * 8 j * 64 lanes * 8
#define W2F_L 16384          // 4 kb * 8 j * 64 lanes * 8

typedef __attribute__((ext_vector_type(8))) short bf16x8;
typedef __attribute__((ext_vector_type(4))) float f32x4;

__device__ __forceinline__ float silu_f(float v) {
    return v / (1.0f + expf(-v));
}

__device__ __forceinline__ unsigned short f2bf(float f) {
    union { float f; unsigned int u; } v; v.f = f;
    unsigned int r = v.u + 0x7FFFu + ((v.u >> 16) & 1u);
    return (unsigned short)(r >> 16);
}

__device__ __forceinline__ float bf2f(unsigned short h) {
    union { unsigned int u; float f; } t; t.u = ((unsigned int)h) << 16;
    return t.f;
}

// split f32 into bf16 hi + bf16 lo (x ~= hi + lo, ~17 mantissa bits)
__device__ __forceinline__ void split2(float v, short& hi, short& lo) {
    unsigned short h = f2bf(v);
    hi = (short)h;
    lo = (short)f2bf(v - bf2f(h));
}

// ---------------- CSR build ----------------

__global__ void k_count(const int* __restrict__ edges, int* __restrict__ degB) {
    int e = blockIdx.x * 256 + threadIdx.x;
    if (e < EBK) atomicAdd(&degB[edges[e]], 1);
}

__global__ void k_scan(const int* __restrict__ degB, int* __restrict__ offB) {
    __shared__ int s[1024];
    __shared__ int carry;
    if (threadIdx.x == 0) carry = 0;
    __syncthreads();
    for (int base = 0; base < NBLK; base += 1024) {
        int i = base + threadIdx.x;
        int v = (i < NBLK) ? degB[i] : 0;
        s[threadIdx.x] = v;
        __syncthreads();
        for (int d = 1; d < 1024; d <<= 1) {
            int t = (threadIdx.x >= d) ? s[threadIdx.x - d] : 0;
            __syncthreads();
            s[threadIdx.x] += t;
            __syncthreads();
        }
        if (i < NBLK) offB[i] = carry + s[threadIdx.x] - v;
        int tot = s[1023];
        __syncthreads();
        if (threadIdx.x == 0) carry += tot;
        __syncthreads();
    }
    if (threadIdx.x == 0) offB[NBLK] = carry;
}

__global__ void k_fill(const int* __restrict__ edges, const int* __restrict__ offB,
                       int* __restrict__ cursor, int* __restrict__ listE) {
    int e = blockIdx.x * 256 + threadIdx.x;
    if (e < EBK) {
        int b = edges[e];
        int p = atomicAdd(&cursor[b], 1);
        listE[offB[b] + p] = e;
    }
}

// top-3 nearest dst atoms per src atom; exact f32, tie -> lower index (matches top_k)
__global__ void k_topk(const int* __restrict__ edges, const float* __restrict__ Z,
                       int* __restrict__ colIdx) {
    int t = blockIdx.x * 256 + threadIdx.x;
    if (t >= EBK * UU) return;
    int e = t >> 2, u = t & 3;
    int b0 = edges[e], b1 = edges[EBK + e];
    int s = b0 * UU + u;
    float zs0 = Z[s*3+0], zs1 = Z[s*3+1], zs2 = Z[s*3+2];
    float d2[UU];
    #pragma unroll
    for (int v = 0; v < UU; v++) {
        int d = b1 * UU + v;
        float a0 = __fsub_rn(zs0, Z[d*3+0]);
        float a1 = __fsub_rn(zs1, Z[d*3+1]);
        float a2 = __fsub_rn(zs2, Z[d*3+2]);
        float p0 = __fmul_rn(a0, a0);
        float p1 = __fmul_rn(a1, a1);
        float p2 = __fmul_rn(a2, a2);
        d2[v] = __fadd_rn(__fadd_rn(p0, p1), p2);
    }
    bool used[UU] = {false, false, false, false};
    #pragma unroll
    for (int k = 0; k < KNN; k++) {
        int best = -1;
        float bd = INFINITY;
        #pragma unroll
        for (int v = 0; v < UU; v++) {
            if (!used[v] && d2[v] < bd) { bd = d2[v]; best = v; }
        }
        used[best] = true;
        colIdx[t * KNN + k] = b1 * UU + best;
    }
}

// ---------------- weight fragment precompute (hi/lo bf16, MFMA B-layout) ----------------
// frag chunk (kb,j): lane l holds W[kb*32 + (l>>4)*8 + t][j*16 + (l&15)], t=0..7

__global__ void k_wfrag(const float* __restrict__ ew1, const float* __restrict__ ew2,
                        const float* __restrict__ cw1,
                        unsigned short* __restrict__ w1f_hi, unsigned short* __restrict__ w1f_lo,
                        unsigned short* __restrict__ w2f_hi, unsigned short* __restrict__ w2f_lo,
                        unsigned short* __restrict__ c1f_hi, unsigned short* __restrict__ c1f_lo) {
    int i = blockIdx.x * 256 + threadIdx.x;
    float v;
    unsigned short* dh;
    unsigned short* dl;
    int di;
    if (i < 3 * W1F_L) {
        int l = i / W1F_L, rem = i % W1F_L;
        int chunk = rem >> 9, lane = (rem >> 3) & 63, t = rem & 7;
        int kb = chunk >> 3, j = chunk & 7;
        int k = kb*32 + (lane >> 4)*8 + t, n = j*16 + (lane & 15);
        v = (k < 273) ? ew1[(size_t)l*273*128 + (size_t)k*128 + n] : 0.f;
        dh = w1f_hi; dl = w1f_lo; di = i;
    } else {
        int i2 = i - 3 * W1F_L;
        if (i2 < 3 * W2F_L) {
            int l = i2 / W2F_L, rem = i2 % W2F_L;
            int chunk = rem >> 9, lane = (rem >> 3) & 63, t = rem & 7;
            int kb = chunk >> 3, j = chunk & 7;
            int k = kb*32 + (lane >> 4)*8 + t, n = j*16 + (lane & 15);
            v = ew2[(size_t)l*128*128 + (size_t)k*128 + n];
            dh = w2f_hi; dl = w2f_lo; di = i2;
        } else {
            int i3 = i2 - 3 * W2F_L;
            if (i3 >= 3 * W2F_L) return;
            int l = i3 / W2F_L, rem = i3 % W2F_L;
            int chunk = rem >> 9, lane = (rem >> 3) & 63, t = rem & 7;
            int kb = chunk >> 3, j = chunk & 7;
            int k = kb*32 + (lane >> 4)*8 + t, n = j*16 + (lane & 15);
            v = cw1[(size_t)l*128*128 + (size_t)k*128 + n];
            dh = c1f_hi; dl = c1f_lo; di = i3;
        }
    }
    short hi, lo;
    split2(v, hi, lo);
    dh[di] = (unsigned short)hi;
    dl[di] = (unsigned short)lo;
}

// ---------------- fused per-src-block edge pipeline (split-bf16 MFMA) ----------------
// 1 wave per src block; exclusive ownership of agg rows b*4..b*4+3 and xnext rows.
// Each GEMM uses 3 MFMAs (hi*Whi + lo*Whi + hi*Wlo) ~= f32 precision.

__global__ __launch_bounds__(64) void k_edge_mfma(
    const float* __restrict__ hbuf,
    const float* __restrict__ x,
    const float* __restrict__ eattr,
    const int* __restrict__ colIdx,
    const int* __restrict__ offB,
    const int* __restrict__ listE,
    const unsigned short* __restrict__ w1f_hi, const unsigned short* __restrict__ w1f_lo,
    const unsigned short* __restrict__ w2f_hi, const unsigned short* __restrict__ w2f_lo,
    const unsigned short* __restrict__ c1f_hi, const unsigned short* __restrict__ c1f_lo,
    const float* __restrict__ eb1,
    const float* __restrict__ eb2,
    const float* __restrict__ cb1,
    const float* __restrict__ cw2v,
    float* __restrict__ agg,
    float* __restrict__ xnext)
{
    const int b = blockIdx.x;
    const int o0 = offB[b];
    const int deg = offB[b + 1] - o0;
    if (deg == 0) return;

    __shared__ unsigned short C1h[16 * 128], C1l[16 * 128];   // swizzled [e][n]
    __shared__ unsigned short Mh[16 * 128],  Ml[16 * 128];    // swizzled [e][n]
    __shared__ float aggS[4 * 128];
    __shared__ float xaccS[12];
    __shared__ float diffS[16 * 3];
    __shared__ int   rowAtomS[16];

    const int l = threadIdx.x;
    const int g = l >> 4, er = l & 15;

    #pragma unroll
    for (int i = 0; i < 8; i++) aggS[i * 64 + l] = 0.f;
    if (l < 12) xaccS[l] = 0.f;

    const int rows = deg * 12;
    const int mtiles = (rows + 15) >> 4;

    for (int mt = 0; mt < mtiles; mt++) {
        __syncthreads();
        // ---- gather A-fragments (f32 load, split to hi/lo) ----
        const int r = mt * 16 + er;
        const bool valid = (r < rows);
        const int j = valid ? (r / 12) : 0;
        const int rr = valid ? (r - j * 12) : 0;
        const int u = rr / 3;
        const int kk = rr - u * 3;
        const int be = listE[o0 + j];
        const int srcatom = b * 4 + u;
        const int colatom = valid ? colIdx[(be * 4 + u) * 3 + kk] : srcatom;

        bf16x8 ah[9], al[9];
        if (valid) {
            const float* hs = hbuf + (size_t)srcatom * 128;
            const float* hc = hbuf + (size_t)colatom * 128;
            #pragma unroll
            for (int kb = 0; kb < 4; kb++) {
                const float* p0 = hs + kb * 32 + g * 8;
                float4 v0 = *(const float4*)(p0);
                float4 v1 = *(const float4*)(p0 + 4);
                float vv[8] = {v0.x, v0.y, v0.z, v0.w, v1.x, v1.y, v1.z, v1.w};
                bf16x8 h8, l8;
                #pragma unroll
                for (int t = 0; t < 8; t++) { short hh, ll; split2(vv[t], hh, ll); h8[t] = hh; l8[t] = ll; }
                ah[kb] = h8; al[kb] = l8;
            }
            #pragma unroll
            for (int kb = 0; kb < 4; kb++) {
                const float* p0 = hc + kb * 32 + g * 8;
                float4 v0 = *(const float4*)(p0);
                float4 v1 = *(const float4*)(p0 + 4);
                float vv[8] = {v0.x, v0.y, v0.z, v0.w, v1.x, v1.y, v1.z, v1.w};
                bf16x8 h8, l8;
                #pragma unroll
                for (int t = 0; t < 8; t++) { short hh, ll; split2(vv[t], hh, ll); h8[t] = hh; l8[t] = ll; }
                ah[4 + kb] = h8; al[4 + kb] = l8;
            }
        } else {
            bf16x8 z = {0, 0, 0, 0, 0, 0, 0, 0};
            #pragma unroll
            for (int kb = 0; kb < 8; kb++) { ah[kb] = z; al[kb] = z; }
        }
        // tail slice k in [256,288): radial, eattr, zero-pad
        {
            float tv[8];
            #pragma unroll
            for (int t = 0; t < 8; t++) tv[t] = 0.f;
            if (valid) {
                if (g == 0) {
                    float dx = x[srcatom*3+0] - x[colatom*3+0];
                    float dy = x[srcatom*3+1] - x[colatom*3+1];
                    float dz = x[srcatom*3+2] - x[colatom*3+2];
                    tv[0] = dx*dx + dy*dy + dz*dz;
                    #pragma unroll
                    for (int t = 1; t < 8; t++) tv[t] = eattr[(size_t)be*16 + (t-1)];
                    diffS[er*3+0] = dx; diffS[er*3+1] = dy; diffS[er*3+2] = dz;
                } else if (g == 1) {
                    #pragma unroll
                    for (int t = 0; t < 8; t++) tv[t] = eattr[(size_t)be*16 + 7 + t];
                } else if (g == 2) {
                    tv[0] = eattr[(size_t)be*16 + 15];
                }
            } else if (g == 0) {
                diffS[er*3+0] = 0.f; diffS[er*3+1] = 0.f; diffS[er*3+2] = 0.f;
            }
            bf16x8 h8, l8;
            #pragma unroll
            for (int t = 0; t < 8; t++) { short hh, ll; split2(tv[t], hh, ll); h8[t] = hh; l8[t] = ll; }
            ah[8] = h8; al[8] = l8;
        }
        if (g == 0) rowAtomS[er] = valid ? u : -1;

        // ---- phase 1: C1 = silu([h_r|h_c|rad|ea] @ W1 + b1), K=288 ----
        f32x4 acc[8];
        #pragma unroll
        for (int jj = 0; jj < 8; jj++) acc[jj] = (f32x4){0.f, 0.f, 0.f, 0.f};
        #pragma unroll
        for (int kb = 0; kb < 9; kb++) {
            #pragma unroll
            for (int jj = 0; jj < 8; jj++) {
                const int off = ((kb * 8 + jj) << 9) + (l << 3);
                bf16x8 wh = *(const bf16x8*)(w1f_hi + off);
                bf16x8 wl = *(const bf16x8*)(w1f_lo + off);
                acc[jj] = __builtin_amdgcn_mfma_f32_16x16x32_bf16(ah[kb], wh, acc[jj], 0, 0, 0);
                acc[jj] = __builtin_amdgcn_mfma_f32_16x16x32_bf16(al[kb], wh, acc[jj], 0, 0, 0);
                acc[jj] = __builtin_amdgcn_mfma_f32_16x16x32_bf16(ah[kb], wl, acc[jj], 0, 0, 0);
            }
        }
        #pragma unroll
        for (int jj = 0; jj < 8; jj++) {
            const int n = jj * 16 + er;
            const float bv = eb1[n];
            #pragma unroll
            for (int reg = 0; reg < 4; reg++) {
                const int e = g * 4 + reg;
                float v = silu_f(acc[jj][reg] + bv);
                short hh, ll; split2(v, hh, ll);
                const int sidx = e * 128 + (n ^ ((e & 7) << 3));
                C1h[sidx] = (unsigned short)hh;
                C1l[sidx] = (unsigned short)ll;
            }
        }
        __syncthreads();

        // ---- phase 2: m = silu(C1 @ W2 + b2) ----
        f32x4 acc2[8];
        #pragma unroll
        for (int jj = 0; jj < 8; jj++) acc2[jj] = (f32x4){0.f, 0.f, 0.f, 0.f};
        #pragma unroll
        for (int kb = 0; kb < 4; kb++) {
            const int aoff = er * 128 + ((kb * 32 + g * 8) ^ ((er & 7) << 3));
            bf16x8 a2h = *(const bf16x8*)&C1h[aoff];
            bf16x8 a2l = *(const bf16x8*)&C1l[aoff];
            #pragma unroll
            for (int jj = 0; jj < 8; jj++) {
                const int off = ((kb * 8 + jj) << 9) + (l << 3);
                bf16x8 wh = *(const bf16x8*)(w2f_hi + off);
                bf16x8 wl = *(const bf16x8*)(w2f_lo + off);
                acc2[jj] = __builtin_amdgcn_mfma_f32_16x16x32_bf16(a2h, wh, acc2[jj], 0, 0, 0);
                acc2[jj] = __builtin_amdgcn_mfma_f32_16x16x32_bf16(a2l, wh, acc2[jj], 0, 0, 0);
                acc2[jj] = __builtin_amdgcn_mfma_f32_16x16x32_bf16(a2h, wl, acc2[jj], 0, 0, 0);
            }
        }
        #pragma unroll
        for (int jj = 0; jj < 8; jj++) {
            const int n = jj * 16 + er;
            const float bv = eb2[n];
            #pragma unroll
            for (int reg = 0; reg < 4; reg++) {
                const int e = g * 4 + reg;
                float v = silu_f(acc2[jj][reg] + bv);
                const int u_c = rowAtomS[e];
                if (u_c >= 0) atomicAdd(&aggS[u_c * 128 + n], v);
                short hh, ll; split2(v, hh, ll);
                const int sidx = e * 128 + (n ^ ((e & 7) << 3));
                Mh[sidx] = (unsigned short)hh;
                Ml[sidx] = (unsigned short)ll;
            }
        }
        __syncthreads();

        // ---- phase 3: s = silu(m @ CW1 + cb1) @ cw2 ----
        f32x4 acc3[8];
        #pragma unroll
        for (int jj = 0; jj < 8; jj++) acc3[jj] = (f32x4){0.f, 0.f, 0.f, 0.f};
        #pragma unroll
        for (int kb = 0; kb < 4; kb++) {
            const int aoff = er * 128 + ((kb * 32 + g * 8) ^ ((er & 7) << 3));
            bf16x8 a3h = *(const bf16x8*)&Mh[aoff];
            bf16x8 a3l = *(const bf16x8*)&Ml[aoff];
            #pragma unroll
            for (int jj = 0; jj < 8; jj++) {
                const int off = ((kb * 8 + jj) << 9) + (l << 3);
                bf16x8 wh = *(const bf16x8*)(c1f_hi + off);
                bf16x8 wl = *(const bf16x8*)(c1f_lo + off);
                acc3[jj] = __builtin_amdgcn_mfma_f32_16x16x32_bf16(a3h, wh, acc3[jj], 0, 0, 0);
                acc3[jj] = __builtin_amdgcn_mfma_f32_16x16x32_bf16(a3l, wh, acc3[jj], 0, 0, 0);
                acc3[jj] = __builtin_amdgcn_mfma_f32_16x16x32_bf16(a3h, wl, acc3[jj], 0, 0, 0);
            }
        }
        float p[4] = {0.f, 0.f, 0.f, 0.f};
        #pragma unroll
        for (int jj = 0; jj < 8; jj++) {
            const int n = jj * 16 + er;
            const float cb = cb1[n], cw = cw2v[n];
            #pragma unroll
            for (int reg = 0; reg < 4; reg++)
                p[reg] += silu_f(acc3[jj][reg] + cb) * cw;
        }
        #pragma unroll
        for (int d = 1; d < 16; d <<= 1) {
            #pragma unroll
            for (int reg = 0; reg < 4; reg++)
                p[reg] += __shfl_xor(p[reg], d);
        }
        if (er == 0) {
            #pragma unroll
            for (int reg = 0; reg < 4; reg++) {
                const int e = g * 4 + reg;
                const int u_c = rowAtomS[e];
                if (u_c >= 0) {
                    atomicAdd(&xaccS[u_c * 3 + 0], diffS[e * 3 + 0] * p[reg]);
                    atomicAdd(&xaccS[u_c * 3 + 1], diffS[e * 3 + 1] * p[reg]);
                    atomicAdd(&xaccS[u_c * 3 + 2], diffS[e * 3 + 2] * p[reg]);
                }
            }
        }
    }
    __syncthreads();
    // exclusive-ownership final stores
    #pragma unroll
    for (int i = 0; i < 8; i++) {
        const int idx = i * 64 + l;
        agg[(size_t)b * 512 + idx] = aggS[idx];
    }
    if (l < 12) {
        const int u2 = l / 3, d = l - u2 * 3;
        const int a = b * 4 + u2;
        xnext[a * 3 + d] = x[a * 3 + d] + xaccS[l] / (3.0f * (float)deg);
    }
}

// ---------------- generic tiled f32 GEMM (node / emb MLPs) ----------------

template<int KT, bool DOSILU, bool DORES, bool SPLIT>
__global__ __launch_bounds__(128) void k_gemm(
    const float* __restrict__ A0, const float* __restrict__ A1,
    const float* __restrict__ W, const float* __restrict__ bias,
    const float* __restrict__ R, float* __restrict__ C, int M)
{
    __shared__ float At[KT][32];
    __shared__ float Bs[32][128];
    const int tid = threadIdx.x;
    const int tile0 = blockIdx.x * 32;
    const int r = tid >> 2, part = tid & 3;
    const int gr = tile0 + r;

    if (gr < M) {
        const float* a0r = A0 + (size_t)gr * 128;
        #pragma unroll
        for (int j = 0; j < 8; j++) {
            int c = part * 32 + j * 4;
            float4 v = *(const float4*)(a0r + c);
            At[c][r] = v.x; At[c+1][r] = v.y; At[c+2][r] = v.z; At[c+3][r] = v.w;
        }
        if (SPLIT) {
            const float* a1r = A1 + (size_t)gr * 128;
            #pragma unroll
            for (int j = 0; j < 8; j++) {
                int c = part * 32 + j * 4;
                float4 v = *(const float4*)(a1r + c);
                At[128+c][r] = v.x; At[129+c][r] = v.y; At[130+c][r] = v.z; At[131+c][r] = v.w;
            }
        }
    } else {
        #pragma unroll
        for (int j = 0; j < 8; j++) {
            int c = part * 32 + j * 4;
            At[c][r] = 0.f; At[c+1][r] = 0.f; At[c+2][r] = 0.f; At[c+3][r] = 0.f;
            if (SPLIT) { At[128+c][r] = 0.f; At[129+c][r] = 0.f; At[130+c][r] = 0.f; At[131+c][r] = 0.f; }
        }
    }

    float acc[4][8];
    #pragma unroll
    for (int i = 0; i < 4; i++)
        #pragma unroll
        for (int j = 0; j < 8; j++) acc[i][j] = 0.f;

    const int tx = tid & 15, ty = tid >> 4;

    for (int kb = 0; kb < KT / 32; kb++) {
        __syncthreads();
        #pragma unroll
        for (int j = 0; j < 8; j++) {
            int li = j * 512 + tid * 4;
            int kk = li >> 7, c = li & 127;
            float4 v = *(const float4*)(W + (size_t)(kb * 32 + kk) * 128 + c);
            *(float4*)&Bs[kk][c] = v;
        }
        __syncthreads();
        #pragma unroll 8
        for (int kk = 0; kk < 32; kk++) {
            float4 a  = *(const float4*)&At[kb * 32 + kk][ty * 4];
            float4 b0 = *(const float4*)&Bs[kk][tx * 8];
            float4 b1 = *(const float4*)&Bs[kk][tx * 8 + 4];
            float av[4] = {a.x, a.y, a.z, a.w};
            float bv[8] = {b0.x, b0.y, b0.z, b0.w, b1.x, b1.y, b1.z, b1.w};
            #pragma unroll
            for (int i = 0; i < 4; i++)
                #pragma unroll
                for (int j = 0; j < 8; j++)
                    acc[i][j] = fmaf(av[i], bv[j], acc[i][j]);
        }
    }

    #pragma unroll
    for (int i = 0; i < 4; i++) {
        int grr = tile0 + ty * 4 + i;
        if (grr >= M) continue;
        #pragma unroll
        for (int j = 0; j < 8; j++) {
            int c = tx * 8 + j;
            float v = acc[i][j] + bias[c];
            if (DOSILU) v = v / (1.0f + expf(-v));
            if (DORES)  v += R[(size_t)grr * 128 + c];
            C[(size_t)grr * 128 + c] = v;
        }
    }
}

// ---------------- launch ----------------

extern "C" void kernel_launch(void* const* d_in, const int* in_sizes, int n_in,
                              void* d_out, int out_size, void* d_ws, size_t ws_size,
                              hipStream_t stream) {
    const float* H        = (const float*)d_in[0];
    const float* Z        = (const float*)d_in[1];
    const int*   edges    = (const int*)  d_in[4];
    const float* eattr    = (const float*)d_in[5];
    const float* emb_in_w = (const float*)d_in[6];
    const float* emb_in_b = (const float*)d_in[7];
    const float* emb_out_w= (const float*)d_in[8];
    const float* emb_out_b= (const float*)d_in[9];
    const float* edge_w1  = (const float*)d_in[10];
    const float* edge_b1  = (const float*)d_in[11];
    const float* edge_w2  = (const float*)d_in[12];
    const float* edge_b2  = (const float*)d_in[13];
    const float* node_w1  = (const float*)d_in[14];
    const float* node_b1  = (const float*)d_in[15];
    const float* node_w2  = (const float*)d_in[16];
    const float* node_b2  = (const float*)d_in[17];
    const float* coord_w1 = (const float*)d_in[18];
    const float* coord_b1 = (const float*)d_in[19];
    const float* coord_w2 = (const float*)d_in[20];

    float* out  = (float*)d_out;
    float* hbuf = out;                              // [N][128]
    float* xout = out + (size_t)NATOM * 128;        // [N][3]

    // workspace (~45.8 MB), 16B-aligned sections
    char* w = (char*)d_ws;
    float* agg = (float*)w;            w += (size_t)NATOM * 128 * 4;       // 40.96 MB
    float* xA  = (float*)w;            w += (size_t)NATOM * 3 * 4;
    float* xB  = (float*)w;            w += (size_t)NATOM * 3 * 4;
    unsigned short* w1f_hi = (unsigned short*)w;  w += (size_t)3 * W1F_L * 2;
    unsigned short* w1f_lo = (unsigned short*)w;  w += (size_t)3 * W1F_L * 2;
    unsigned short* w2f_hi = (unsigned short*)w;  w += (size_t)3 * W2F_L * 2;
    unsigned short* w2f_lo = (unsigned short*)w;  w += (size_t)3 * W2F_L * 2;
    unsigned short* c1f_hi = (unsigned short*)w;  w += (size_t)3 * W2F_L * 2;
    unsigned short* c1f_lo = (unsigned short*)w;  w += (size_t)3 * W2F_L * 2;
    int* colIdx = (int*)w;             w += (size_t)EALL * 4;
    int* degB   = (int*)w;             w += (size_t)NBLK * 4;
    int* cursor = (int*)w;             w += (size_t)NBLK * 4;
    int* listE  = (int*)w;             w += (size_t)EBK * 4;
    int* offB   = (int*)w;             w += (size_t)(NBLK + 1) * 4;

    hipMemsetAsync(degB,   0, NBLK * sizeof(int), stream);
    hipMemsetAsync(cursor, 0, NBLK * sizeof(int), stream);

    k_count<<<(EBK + 255) / 256, 256, 0, stream>>>(edges, degB);
    k_scan <<<1, 1024, 0, stream>>>(degB, offB);
    k_fill <<<(EBK + 255) / 256, 256, 0, stream>>>(edges, offB, cursor, listE);
    k_topk <<<(EBK * UU + 255) / 256, 256, 0, stream>>>(edges, Z, colIdx);

    {
        int total = 3 * W1F_L + 3 * W2F_L + 3 * W2F_L;
        k_wfrag<<<(total + 255) / 256, 256, 0, stream>>>(
            edge_w1, edge_w2, coord_w1,
            w1f_hi, w1f_lo, w2f_hi, w2f_lo, c1f_hi, c1f_lo);
    }

    // h = H @ emb_in_w + b
    k_gemm<128, false, false, false><<<NATOM / 32, 128, 0, stream>>>(
        H, nullptr, emb_in_w, emb_in_b, nullptr, hbuf, NATOM);

    const float* xcur = Z;
    for (int l = 0; l < LAY; l++) {
        float* xnext = (l == 0) ? xA : (l == 1) ? xB : xout;

        hipMemcpyAsync(xnext, xcur, (size_t)NATOM * 3 * sizeof(float),
                       hipMemcpyDeviceToDevice, stream);
        hipMemsetAsync(agg, 0, (size_t)NATOM * 128 * sizeof(float), stream);

        k_edge_mfma<<<NBLK, 64, 0, stream>>>(
            hbuf, xcur, eattr, colIdx, offB, listE,
            w1f_hi + (size_t)l * W1F_L, w1f_lo + (size_t)l * W1F_L,
            w2f_hi + (size_t)l * W2F_L, w2f_lo + (size_t)l * W2F_L,
            c1f_hi + (size_t)l * W2F_L, c1f_lo + (size_t)l * W2F_L,
            edge_b1 + l * 128, edge_b2 + l * 128, coord_b1 + l * 128, coord_w2 + l * 128,
            agg, xnext);

        // node MLP: hidden = silu([h|agg] @ w1 + b1)  (in-place into agg)
        k_gemm<256, true, false, true><<<NATOM / 32, 128, 0, stream>>>(
            hbuf, agg, node_w1 + (size_t)l * 256 * 128, node_b1 + l * 128,
            nullptr, agg, NATOM);
        // h += hidden @ w2 + b2
        k_gemm<128, false, true, false><<<NATOM / 32, 128, 0, stream>>>(
            agg, nullptr, node_w2 + (size_t)l * 128 * 128, node_b2 + l * 128,
            hbuf, hbuf, NATOM);

        xcur = xnext;
    }

    k_gemm<128, false, false, false><<<NATOM / 32, 128, 0, stream>>>(
        hbuf, nullptr, emb_out_w, emb_out_b, nullptr, hbuf, NATOM);
}

// Round 5
// 3821.140 us; speedup vs baseline: 2.8233x; 2.8233x over previous
//
#include <hip/hip_runtime.h>
#include <math.h>

#define HIDC 128
#define EDGEF 16
#define LAY 3
#define KNN 3
#define UU 4
#define NBLK 20000
#define NATOM (NBLK*UU)      // 80000
#define EBK 30000
#define EALL (EBK*UU*KNN)    // 360000

#define W1F_L 36864          // 9 kb * 8 j * 64 lanes * 8
#define W2F_L 16384          // 4 kb * 8 j * 64 lanes * 8

typedef __attribute__((ext_vector_type(8))) short bf16x8;
typedef __attribute__((ext_vector_type(4))) float f32x4;

__device__ __forceinline__ float silu_f(float v) {
    return v / (1.0f + expf(-v));
}

__device__ __forceinline__ unsigned short f2bf(float f) {
    union { float f; unsigned int u; } v; v.f = f;
    unsigned int r = v.u + 0x7FFFu + ((v.u >> 16) & 1u);
    return (unsigned short)(r >> 16);
}

__device__ __forceinline__ float bf2f(unsigned short h) {
    union { unsigned int u; float f; } t; t.u = ((unsigned int)h) << 16;
    return t.f;
}

// split f32 into bf16 hi + bf16 lo (x ~= hi + lo, ~17 mantissa bits)
__device__ __forceinline__ void split2(float v, short& hi, short& lo) {
    unsigned short h = f2bf(v);
    hi = (short)h;
    lo = (short)f2bf(v - bf2f(h));
}

// ---------------- CSR build ----------------

__global__ void k_count(const int* __restrict__ edges, int* __restrict__ degB) {
    int e = blockIdx.x * 256 + threadIdx.x;
    if (e < EBK) atomicAdd(&degB[edges[e]], 1);
}

__global__ void k_scan(const int* __restrict__ degB, int* __restrict__ offB) {
    __shared__ int s[1024];
    __shared__ int carry;
    if (threadIdx.x == 0) carry = 0;
    __syncthreads();
    for (int base = 0; base < NBLK; base += 1024) {
        int i = base + threadIdx.x;
        int v = (i < NBLK) ? degB[i] : 0;
        s[threadIdx.x] = v;
        __syncthreads();
        for (int d = 1; d < 1024; d <<= 1) {
            int t = (threadIdx.x >= d) ? s[threadIdx.x - d] : 0;
            __syncthreads();
            s[threadIdx.x] += t;
            __syncthreads();
        }
        if (i < NBLK) offB[i] = carry + s[threadIdx.x] - v;
        int tot = s[1023];
        __syncthreads();
        if (threadIdx.x == 0) carry += tot;
        __syncthreads();
    }
    if (threadIdx.x == 0) offB[NBLK] = carry;
}

__global__ void k_fill(const int* __restrict__ edges, const int* __restrict__ offB,
                       int* __restrict__ cursor, int* __restrict__ listE) {
    int e = blockIdx.x * 256 + threadIdx.x;
    if (e < EBK) {
        int b = edges[e];
        int p = atomicAdd(&cursor[b], 1);
        listE[offB[b] + p] = e;
    }
}

// top-3 nearest dst atoms per src atom; exact f32, tie -> lower index (matches top_k)
__global__ void k_topk(const int* __restrict__ edges, const float* __restrict__ Z,
                       int* __restrict__ colIdx) {
    int t = blockIdx.x * 256 + threadIdx.x;
    if (t >= EBK * UU) return;
    int e = t >> 2, u = t & 3;
    int b0 = edges[e], b1 = edges[EBK + e];
    int s = b0 * UU + u;
    float zs0 = Z[s*3+0], zs1 = Z[s*3+1], zs2 = Z[s*3+2];
    float d2[UU];
    #pragma unroll
    for (int v = 0; v < UU; v++) {
        int d = b1 * UU + v;
        float a0 = __fsub_rn(zs0, Z[d*3+0]);
        float a1 = __fsub_rn(zs1, Z[d*3+1]);
        float a2 = __fsub_rn(zs2, Z[d*3+2]);
        float p0 = __fmul_rn(a0, a0);
        float p1 = __fmul_rn(a1, a1);
        float p2 = __fmul_rn(a2, a2);
        d2[v] = __fadd_rn(__fadd_rn(p0, p1), p2);
    }
    bool used[UU] = {false, false, false, false};
    #pragma unroll
    for (int k = 0; k < KNN; k++) {
        int best = -1;
        float bd = INFINITY;
        #pragma unroll
        for (int v = 0; v < UU; v++) {
            if (!used[v] && d2[v] < bd) { bd = d2[v]; best = v; }
        }
        used[best] = true;
        colIdx[t * KNN + k] = b1 * UU + best;
    }
}

// ---------------- weight fragment precompute (hi/lo bf16, MFMA B-layout) ----------------
// frag chunk (kb,j): lane l holds W[kb*32 + (l>>4)*8 + t][j*16 + (l&15)], t=0..7

__global__ void k_wfrag(const float* __restrict__ ew1, const float* __restrict__ ew2,
                        const float* __restrict__ cw1,
                        unsigned short* __restrict__ w1f_hi, unsigned short* __restrict__ w1f_lo,
                        unsigned short* __restrict__ w2f_hi, unsigned short* __restrict__ w2f_lo,
                        unsigned short* __restrict__ c1f_hi, unsigned short* __restrict__ c1f_lo) {
    int i = blockIdx.x * 256 + threadIdx.x;
    float v;
    unsigned short* dh;
    unsigned short* dl;
    int di;
    if (i < 3 * W1F_L) {
        int l = i / W1F_L, rem = i % W1F_L;
        int chunk = rem >> 9, lane = (rem >> 3) & 63, t = rem & 7;
        int kb = chunk >> 3, j = chunk & 7;
        int k = kb*32 + (lane >> 4)*8 + t, n = j*16 + (lane & 15);
        v = (k < 273) ? ew1[(size_t)l*273*128 + (size_t)k*128 + n] : 0.f;
        dh = w1f_hi; dl = w1f_lo; di = i;
    } else {
        int i2 = i - 3 * W1F_L;
        if (i2 < 3 * W2F_L) {
            int l = i2 / W2F_L, rem = i2 % W2F_L;
            int chunk = rem >> 9, lane = (rem >> 3) & 63, t = rem & 7;
            int kb = chunk >> 3, j = chunk & 7;
            int k = kb*32 + (lane >> 4)*8 + t, n = j*16 + (lane & 15);
            v = ew2[(size_t)l*128*128 + (size_t)k*128 + n];
            dh = w2f_hi; dl = w2f_lo; di = i2;
        } else {
            int i3 = i2 - 3 * W2F_L;
            if (i3 >= 3 * W2F_L) return;
            int l = i3 / W2F_L, rem = i3 % W2F_L;
            int chunk = rem >> 9, lane = (rem >> 3) & 63, t = rem & 7;
            int kb = chunk >> 3, j = chunk & 7;
            int k = kb*32 + (lane >> 4)*8 + t, n = j*16 + (lane & 15);
            v = cw1[(size_t)l*128*128 + (size_t)k*128 + n];
            dh = c1f_hi; dl = c1f_lo; di = i3;
        }
    }
    short hi, lo;
    split2(v, hi, lo);
    dh[di] = (unsigned short)hi;
    dl[di] = (unsigned short)lo;
}

// ---------------- fused per-src-block edge pipeline (split-bf16 MFMA) ----------------
// 1 wave per src block; exclusive ownership of agg rows b*4..b*4+3 and xnext rows.
// Each GEMM uses 3 MFMAs (hi*Whi + lo*Whi + hi*Wlo) ~= f32 precision.
// Rolled kb-loops + per-kb fragment build keep VGPR pressure low (no scratch).

__global__ __launch_bounds__(64) void k_edge_mfma(
    const float* __restrict__ hbuf,
    const float* __restrict__ x,
    const float* __restrict__ eattr,
    const int* __restrict__ colIdx,
    const int* __restrict__ offB,
    const int* __restrict__ listE,
    const unsigned short* __restrict__ w1f_hi, const unsigned short* __restrict__ w1f_lo,
    const unsigned short* __restrict__ w2f_hi, const unsigned short* __restrict__ w2f_lo,
    const unsigned short* __restrict__ c1f_hi, const unsigned short* __restrict__ c1f_lo,
    const float* __restrict__ eb1,
    const float* __restrict__ eb2,
    const float* __restrict__ cb1,
    const float* __restrict__ cw2v,
    float* __restrict__ agg,
    float* __restrict__ xnext)
{
    const int b = blockIdx.x;
    const int o0 = offB[b];
    const int deg = offB[b + 1] - o0;
    if (deg == 0) return;

    __shared__ unsigned short C1h[16 * 128], C1l[16 * 128];   // swizzled [e][n]
    __shared__ unsigned short Mh[16 * 128],  Ml[16 * 128];    // swizzled [e][n]
    __shared__ float aggS[4 * 128];
    __shared__ float xaccS[12];
    __shared__ float diffS[16 * 3];
    __shared__ int   rowAtomS[16];

    const int l = threadIdx.x;
    const int g = l >> 4, er = l & 15;

    #pragma unroll
    for (int i = 0; i < 8; i++) aggS[i * 64 + l] = 0.f;
    if (l < 12) xaccS[l] = 0.f;

    const int rows = deg * 12;
    const int mtiles = (rows + 15) >> 4;

    for (int mt = 0; mt < mtiles; mt++) {
        __syncthreads();
        // ---- per-lane edge-row indices ----
        const int r = mt * 16 + er;
        const bool valid = (r < rows);
        const int j = valid ? (r / 12) : 0;
        const int rr = valid ? (r - j * 12) : 0;
        const int u = rr / 3;
        const int kk = rr - u * 3;
        const int be = listE[o0 + j];
        const int srcatom = b * 4 + u;
        const int colatom = valid ? colIdx[(be * 4 + u) * 3 + kk] : srcatom;
        const float* hs = hbuf + (size_t)srcatom * 128;
        const float* hc = hbuf + (size_t)colatom * 128;

        // ---- tail fragment (k 256..287): radial, eattr, zero-pad ----
        bf16x8 th8, tl8;
        {
            float tv[8];
            #pragma unroll
            for (int t = 0; t < 8; t++) tv[t] = 0.f;
            if (valid) {
                if (g == 0) {
                    float dx = x[srcatom*3+0] - x[colatom*3+0];
                    float dy = x[srcatom*3+1] - x[colatom*3+1];
                    float dz = x[srcatom*3+2] - x[colatom*3+2];
                    tv[0] = dx*dx + dy*dy + dz*dz;
                    #pragma unroll
                    for (int t = 1; t < 8; t++) tv[t] = eattr[(size_t)be*16 + (t-1)];
                    diffS[er*3+0] = dx; diffS[er*3+1] = dy; diffS[er*3+2] = dz;
                } else if (g == 1) {
                    #pragma unroll
                    for (int t = 0; t < 8; t++) tv[t] = eattr[(size_t)be*16 + 7 + t];
                } else if (g == 2) {
                    tv[0] = eattr[(size_t)be*16 + 15];
                }
            } else if (g == 0) {
                diffS[er*3+0] = 0.f; diffS[er*3+1] = 0.f; diffS[er*3+2] = 0.f;
            }
            #pragma unroll
            for (int t = 0; t < 8; t++) { short hh, ll; split2(tv[t], hh, ll); th8[t] = hh; tl8[t] = ll; }
        }
        if (g == 0) rowAtomS[er] = valid ? u : -1;

        // ---- phase 1: C1 = silu([h_r|h_c|rad|ea] @ W1 + b1), K=288 ----
        f32x4 acc[8];
        #pragma unroll
        for (int jj = 0; jj < 8; jj++) acc[jj] = (f32x4){0.f, 0.f, 0.f, 0.f};

        #pragma unroll 1
        for (int kb = 0; kb < 8; kb++) {
            const float* p0 = ((kb < 4) ? (hs + kb * 32) : (hc + (kb - 4) * 32)) + g * 8;
            float4 v0 = *(const float4*)(p0);
            float4 v1 = *(const float4*)(p0 + 4);
            float vv[8] = {v0.x, v0.y, v0.z, v0.w, v1.x, v1.y, v1.z, v1.w};
            bf16x8 afh, afl;
            #pragma unroll
            for (int t = 0; t < 8; t++) {
                float vt = valid ? vv[t] : 0.f;
                short hh, ll; split2(vt, hh, ll);
                afh[t] = hh; afl[t] = ll;
            }
            #pragma unroll
            for (int jj = 0; jj < 8; jj++) {
                const int off = ((kb * 8 + jj) << 9) + (l << 3);
                bf16x8 wh = *(const bf16x8*)(w1f_hi + off);
                bf16x8 wl = *(const bf16x8*)(w1f_lo + off);
                acc[jj] = __builtin_amdgcn_mfma_f32_16x16x32_bf16(afh, wh, acc[jj], 0, 0, 0);
                acc[jj] = __builtin_amdgcn_mfma_f32_16x16x32_bf16(afl, wh, acc[jj], 0, 0, 0);
                acc[jj] = __builtin_amdgcn_mfma_f32_16x16x32_bf16(afh, wl, acc[jj], 0, 0, 0);
            }
        }
        // tail kb == 8
        #pragma unroll
        for (int jj = 0; jj < 8; jj++) {
            const int off = ((8 * 8 + jj) << 9) + (l << 3);
            bf16x8 wh = *(const bf16x8*)(w1f_hi + off);
            bf16x8 wl = *(const bf16x8*)(w1f_lo + off);
            acc[jj] = __builtin_amdgcn_mfma_f32_16x16x32_bf16(th8, wh, acc[jj], 0, 0, 0);
            acc[jj] = __builtin_amdgcn_mfma_f32_16x16x32_bf16(tl8, wh, acc[jj], 0, 0, 0);
            acc[jj] = __builtin_amdgcn_mfma_f32_16x16x32_bf16(th8, wl, acc[jj], 0, 0, 0);
        }
        #pragma unroll
        for (int jj = 0; jj < 8; jj++) {
            const int n = jj * 16 + er;
            const float bv = eb1[n];
            #pragma unroll
            for (int reg = 0; reg < 4; reg++) {
                const int e = g * 4 + reg;
                float v = silu_f(acc[jj][reg] + bv);
                short hh, ll; split2(v, hh, ll);
                const int sidx = e * 128 + (n ^ ((e & 7) << 3));
                C1h[sidx] = (unsigned short)hh;
                C1l[sidx] = (unsigned short)ll;
            }
        }
        __syncthreads();

        // ---- phase 2: m = silu(C1 @ W2 + b2) ----
        f32x4 acc2[8];
        #pragma unroll
        for (int jj = 0; jj < 8; jj++) acc2[jj] = (f32x4){0.f, 0.f, 0.f, 0.f};
        #pragma unroll 1
        for (int kb = 0; kb < 4; kb++) {
            const int aoff = er * 128 + ((kb * 32 + g * 8) ^ ((er & 7) << 3));
            bf16x8 a2h = *(const bf16x8*)&C1h[aoff];
            bf16x8 a2l = *(const bf16x8*)&C1l[aoff];
            #pragma unroll
            for (int jj = 0; jj < 8; jj++) {
                const int off = ((kb * 8 + jj) << 9) + (l << 3);
                bf16x8 wh = *(const bf16x8*)(w2f_hi + off);
                bf16x8 wl = *(const bf16x8*)(w2f_lo + off);
                acc2[jj] = __builtin_amdgcn_mfma_f32_16x16x32_bf16(a2h, wh, acc2[jj], 0, 0, 0);
                acc2[jj] = __builtin_amdgcn_mfma_f32_16x16x32_bf16(a2l, wh, acc2[jj], 0, 0, 0);
                acc2[jj] = __builtin_amdgcn_mfma_f32_16x16x32_bf16(a2h, wl, acc2[jj], 0, 0, 0);
            }
        }
        #pragma unroll
        for (int jj = 0; jj < 8; jj++) {
            const int n = jj * 16 + er;
            const float bv = eb2[n];
            #pragma unroll
            for (int reg = 0; reg < 4; reg++) {
                const int e = g * 4 + reg;
                float v = silu_f(acc2[jj][reg] + bv);
                const int u_c = rowAtomS[e];
                if (u_c >= 0) atomicAdd(&aggS[u_c * 128 + n], v);
                short hh, ll; split2(v, hh, ll);
                const int sidx = e * 128 + (n ^ ((e & 7) << 3));
                Mh[sidx] = (unsigned short)hh;
                Ml[sidx] = (unsigned short)ll;
            }
        }
        __syncthreads();

        // ---- phase 3: s = silu(m @ CW1 + cb1) @ cw2 ----
        f32x4 acc3[8];
        #pragma unroll
        for (int jj = 0; jj < 8; jj++) acc3[jj] = (f32x4){0.f, 0.f, 0.f, 0.f};
        #pragma unroll 1
        for (int kb = 0; kb < 4; kb++) {
            const int aoff = er * 128 + ((kb * 32 + g * 8) ^ ((er & 7) << 3));
            bf16x8 a3h = *(const bf16x8*)&Mh[aoff];
            bf16x8 a3l = *(const bf16x8*)&Ml[aoff];
            #pragma unroll
            for (int jj = 0; jj < 8; jj++) {
                const int off = ((kb * 8 + jj) << 9) + (l << 3);
                bf16x8 wh = *(const bf16x8*)(c1f_hi + off);
                bf16x8 wl = *(const bf16x8*)(c1f_lo + off);
                acc3[jj] = __builtin_amdgcn_mfma_f32_16x16x32_bf16(a3h, wh, acc3[jj], 0, 0, 0);
                acc3[jj] = __builtin_amdgcn_mfma_f32_16x16x32_bf16(a3l, wh, acc3[jj], 0, 0, 0);
                acc3[jj] = __builtin_amdgcn_mfma_f32_16x16x32_bf16(a3h, wl, acc3[jj], 0, 0, 0);
            }
        }
        float p[4] = {0.f, 0.f, 0.f, 0.f};
        #pragma unroll
        for (int jj = 0; jj < 8; jj++) {
            const int n = jj * 16 + er;
            const float cb = cb1[n], cw = cw2v[n];
            #pragma unroll
            for (int reg = 0; reg < 4; reg++)
                p[reg] += silu_f(acc3[jj][reg] + cb) * cw;
        }
        #pragma unroll
        for (int d = 1; d < 16; d <<= 1) {
            #pragma unroll
            for (int reg = 0; reg < 4; reg++)
                p[reg] += __shfl_xor(p[reg], d);
        }
        if (er == 0) {
            #pragma unroll
            for (int reg = 0; reg < 4; reg++) {
                const int e = g * 4 + reg;
                const int u_c = rowAtomS[e];
                if (u_c >= 0) {
                    atomicAdd(&xaccS[u_c * 3 + 0], diffS[e * 3 + 0] * p[reg]);
                    atomicAdd(&xaccS[u_c * 3 + 1], diffS[e * 3 + 1] * p[reg]);
                    atomicAdd(&xaccS[u_c * 3 + 2], diffS[e * 3 + 2] * p[reg]);
                }
            }
        }
    }
    __syncthreads();
    // exclusive-ownership final stores
    #pragma unroll
    for (int i = 0; i < 8; i++) {
        const int idx = i * 64 + l;
        agg[(size_t)b * 512 + idx] = aggS[idx];
    }
    if (l < 12) {
        const int u2 = l / 3, d = l - u2 * 3;
        const int a = b * 4 + u2;
        xnext[a * 3 + d] = x[a * 3 + d] + xaccS[l] / (3.0f * (float)deg);
    }
}

// ---------------- generic tiled f32 GEMM (node / emb MLPs) ----------------

template<int KT, bool DOSILU, bool DORES, bool SPLIT>
__global__ __launch_bounds__(128) void k_gemm(
    const float* __restrict__ A0, const float* __restrict__ A1,
    const float* __restrict__ W, const float* __restrict__ bias,
    const float* __restrict__ R, float* __restrict__ C, int M)
{
    __shared__ float At[KT][32];
    __shared__ float Bs[32][128];
    const int tid = threadIdx.x;
    const int tile0 = blockIdx.x * 32;
    const int r = tid >> 2, part = tid & 3;
    const int gr = tile0 + r;

    if (gr < M) {
        const float* a0r = A0 + (size_t)gr * 128;
        #pragma unroll
        for (int j = 0; j < 8; j++) {
            int c = part * 32 + j * 4;
            float4 v = *(const float4*)(a0r + c);
            At[c][r] = v.x; At[c+1][r] = v.y; At[c+2][r] = v.z; At[c+3][r] = v.w;
        }
        if (SPLIT) {
            const float* a1r = A1 + (size_t)gr * 128;
            #pragma unroll
            for (int j = 0; j < 8; j++) {
                int c = part * 32 + j * 4;
                float4 v = *(const float4*)(a1r + c);
                At[128+c][r] = v.x; At[129+c][r] = v.y; At[130+c][r] = v.z; At[131+c][r] = v.w;
            }
        }
    } else {
        #pragma unroll
        for (int j = 0; j < 8; j++) {
            int c = part * 32 + j * 4;
            At[c][r] = 0.f; At[c+1][r] = 0.f; At[c+2][r] = 0.f; At[c+3][r] = 0.f;
            if (SPLIT) { At[128+c][r] = 0.f; At[129+c][r] = 0.f; At[130+c][r] = 0.f; At[131+c][r] = 0.f; }
        }
    }

    float acc[4][8];
    #pragma unroll
    for (int i = 0; i < 4; i++)
        #pragma unroll
        for (int j = 0; j < 8; j++) acc[i][j] = 0.f;

    const int tx = tid & 15, ty = tid >> 4;

    for (int kb = 0; kb < KT / 32; kb++) {
        __syncthreads();
        #pragma unroll
        for (int j = 0; j < 8; j++) {
            int li = j * 512 + tid * 4;
            int kk = li >> 7, c = li & 127;
            float4 v = *(const float4*)(W + (size_t)(kb * 32 + kk) * 128 + c);
            *(float4*)&Bs[kk][c] = v;
        }
        __syncthreads();
        #pragma unroll 8
        for (int kk = 0; kk < 32; kk++) {
            float4 a  = *(const float4*)&At[kb * 32 + kk][ty * 4];
            float4 b0 = *(const float4*)&Bs[kk][tx * 8];
            float4 b1 = *(const float4*)&Bs[kk][tx * 8 + 4];
            float av[4] = {a.x, a.y, a.z, a.w};
            float bv[8] = {b0.x, b0.y, b0.z, b0.w, b1.x, b1.y, b1.z, b1.w};
            #pragma unroll
            for (int i = 0; i < 4; i++)
                #pragma unroll
                for (int j = 0; j < 8; j++)
                    acc[i][j] = fmaf(av[i], bv[j], acc[i][j]);
        }
    }

    #pragma unroll
    for (int i = 0; i < 4; i++) {
        int grr = tile0 + ty * 4 + i;
        if (grr >= M) continue;
        #pragma unroll
        for (int j = 0; j < 8; j++) {
            int c = tx * 8 + j;
            float v = acc[i][j] + bias[c];
            if (DOSILU) v = v / (1.0f + expf(-v));
            if (DORES)  v += R[(size_t)grr * 128 + c];
            C[(size_t)grr * 128 + c] = v;
        }
    }
}

// ---------------- launch ----------------

extern "C" void kernel_launch(void* const* d_in, const int* in_sizes, int n_in,
                              void* d_out, int out_size, void* d_ws, size_t ws_size,
                              hipStream_t stream) {
    const float* H        = (const float*)d_in[0];
    const float* Z        = (const float*)d_in[1];
    const int*   edges    = (const int*)  d_in[4];
    const float* eattr    = (const float*)d_in[5];
    const float* emb_in_w = (const float*)d_in[6];
    const float* emb_in_b = (const float*)d_in[7];
    const float* emb_out_w= (const float*)d_in[8];
    const float* emb_out_b= (const float*)d_in[9];
    const float* edge_w1  = (const float*)d_in[10];
    const float* edge_b1  = (const float*)d_in[11];
    const float* edge_w2  = (const float*)d_in[12];
    const float* edge_b2  = (const float*)d_in[13];
    const float* node_w1  = (const float*)d_in[14];
    const float* node_b1  = (const float*)d_in[15];
    const float* node_w2  = (const float*)d_in[16];
    const float* node_b2  = (const float*)d_in[17];
    const float* coord_w1 = (const float*)d_in[18];
    const float* coord_b1 = (const float*)d_in[19];
    const float* coord_w2 = (const float*)d_in[20];

    float* out  = (float*)d_out;
    float* hbuf = out;                              // [N][128]
    float* xout = out + (size_t)NATOM * 128;        // [N][3]

    // workspace (~45.8 MB), 16B-aligned sections
    char* w = (char*)d_ws;
    float* agg = (float*)w;            w += (size_t)NATOM * 128 * 4;       // 40.96 MB
    float* xA  = (float*)w;            w += (size_t)NATOM * 3 * 4;
    float* xB  = (float*)w;            w += (size_t)NATOM * 3 * 4;
    unsigned short* w1f_hi = (unsigned short*)w;  w += (size_t)3 * W1F_L * 2;
    unsigned short* w1f_lo = (unsigned short*)w;  w += (size_t)3 * W1F_L * 2;
    unsigned short* w2f_hi = (unsigned short*)w;  w += (size_t)3 * W2F_L * 2;
    unsigned short* w2f_lo = (unsigned short*)w;  w += (size_t)3 * W2F_L * 2;
    unsigned short* c1f_hi = (unsigned short*)w;  w += (size_t)3 * W2F_L * 2;
    unsigned short* c1f_lo = (unsigned short*)w;  w += (size_t)3 * W2F_L * 2;
    int* colIdx = (int*)w;             w += (size_t)EALL * 4;
    int* degB   = (int*)w;             w += (size_t)NBLK * 4;
    int* cursor = (int*)w;             w += (size_t)NBLK * 4;
    int* listE  = (int*)w;             w += (size_t)EBK * 4;
    int* offB   = (int*)w;             w += (size_t)(NBLK + 1) * 4;

    hipMemsetAsync(degB,   0, NBLK * sizeof(int), stream);
    hipMemsetAsync(cursor, 0, NBLK * sizeof(int), stream);

    k_count<<<(EBK + 255) / 256, 256, 0, stream>>>(edges, degB);
    k_scan <<<1, 1024, 0, stream>>>(degB, offB);
    k_fill <<<(EBK + 255) / 256, 256, 0, stream>>>(edges, offB, cursor, listE);
    k_topk <<<(EBK * UU + 255) / 256, 256, 0, stream>>>(edges, Z, colIdx);

    {
        int total = 3 * W1F_L + 3 * W2F_L + 3 * W2F_L;
        k_wfrag<<<(total + 255) / 256, 256, 0, stream>>>(
            edge_w1, edge_w2, coord_w1,
            w1f_hi, w1f_lo, w2f_hi, w2f_lo, c1f_hi, c1f_lo);
    }

    // h = H @ emb_in_w + b
    k_gemm<128, false, false, false><<<NATOM / 32, 128, 0, stream>>>(
        H, nullptr, emb_in_w, emb_in_b, nullptr, hbuf, NATOM);

    const float* xcur = Z;
    for (int l = 0; l < LAY; l++) {
        float* xnext = (l == 0) ? xA : (l == 1) ? xB : xout;

        hipMemcpyAsync(xnext, xcur, (size_t)NATOM * 3 * sizeof(float),
                       hipMemcpyDeviceToDevice, stream);
        hipMemsetAsync(agg, 0, (size_t)NATOM * 128 * sizeof(float), stream);

        k_edge_mfma<<<NBLK, 64, 0, stream>>>(
            hbuf, xcur, eattr, colIdx, offB, listE,
            w1f_hi + (size_t)l * W1F_L, w1f_lo + (size_t)l * W1F_L,
            w2f_hi + (size_t)l * W2F_L, w2f_lo + (size_t)l * W2F_L,
            c1f_hi + (size_t)l * W2F_L, c1f_lo + (size_t)l * W2F_L,
            edge_b1 + l * 128, edge_b2 + l * 128, coord_b1 + l * 128, coord_w2 + l * 128,
            agg, xnext);

        // node MLP: hidden = silu([h|agg] @ w1 + b1)  (in-place into agg)
        k_gemm<256, true, false, true><<<NATOM / 32, 128, 0, stream>>>(
            hbuf, agg, node_w1 + (size_t)l * 256 * 128, node_b1 + l * 128,
            nullptr, agg, NATOM);
        // h += hidden @ w2 + b2
        k_gemm<128, false, true, false><<<NATOM / 32, 128, 0, stream>>>(
            agg, nullptr, node_w2 + (size_t)l * 128 * 128, node_b2 + l * 128,
            hbuf, hbuf, NATOM);

        xcur = xnext;
    }

    k_gemm<128, false, false, false><<<NATOM / 32, 128, 0, stream>>>(
        hbuf, nullptr, emb_out_w, emb_out_b, nullptr, hbuf, NATOM);
}